// Round 13
// baseline (537.196 us; speedup 1.0000x reference)
//
#include <hip/hip_runtime.h>
#include <hip/hip_bf16.h>
#include <hip/hip_fp16.h>

// ---------------------------------------------------------------------------
// GCN graph classifier: 3x GCNConv(128->128) + ReLU, mean-pool(64), linear(10)
// Strategy:
//   * R12: mean-pool FUSED into layer-3 GEMM epilogue (batch sorted -> block's
//     64 rows span 1-2 graphs; LDS[128] atomic accumulate + per-graph flush).
//     Removes pool kernel + 25.6MB h3 round-trip. gcnt computed in fill.
//   * R11: 8-aligned padded CSR; pad slots -> index N (appended zero row);
//     agg inner loop = single uniform 8-batch (uint4 = 8 packed u16 indices).
//   * R10: rows PRE-SCALED by dinv (xs = dinv*x; hs = dinv*relu(...)), agg =
//     pure row sum * dinv[i] (reassociation of D^-1/2 A D^-1/2).
//   * R9: one wave per node (R8 fusion cut gather TLP 16x -> regressed).
//   * R8: csr_src uint16; R7: MFMA GEMM w/ pre-packed W frags
//     (C/D col=lane&15,row=(lane>>4)*4+reg [HW-verified]); R6: fp16 rows;
//     R2: 3-kernel parallel scan.
// ---------------------------------------------------------------------------

#define HID 128
#define NGRAPH 64

typedef _Float16 half8v __attribute__((ext_vector_type(8)));
typedef float floatx4 __attribute__((ext_vector_type(4)));

__device__ __forceinline__ int idx_at(const void* p, long long i, int f64) {
    if (f64) return (int)((const long long*)p)[i];
    return ((const int*)p)[i];
}

// init counts/pooled/gcnt + fill padded csr_src with N (zero-row index);
// block 0 also detects int64-vs-int32 edge_index (odd 32-bit words all zero).
__global__ void init_kernel(const int* __restrict__ ei, int* __restrict__ flag,
                            int* __restrict__ counts, float* __restrict__ pooled,
                            float* __restrict__ gcnt, uint4* __restrict__ csr4,
                            int N, int nCsr4) {
    int i = blockIdx.x * blockDim.x + threadIdx.x;
    int stride = gridDim.x * blockDim.x;
    if (i < N) counts[i] = 0;
    if (i < NGRAPH * HID) pooled[i] = 0.f;
    if (i < NGRAPH) gcnt[i] = 0.f;
    unsigned fillv = (unsigned)N | ((unsigned)N << 16);
    uint4 fv = make_uint4(fillv, fillv, fillv, fillv);
    for (int j = i; j < nCsr4; j += stride) csr4[j] = fv;
    if (blockIdx.x == 0) {
        __shared__ int cnt;
        if (threadIdx.x == 0) cnt = 0;
        __syncthreads();
        int z = 0;
        for (int k = threadIdx.x; k < 2048; k += 256)
            if (ei[2 * k + 1] == 0) z++;
        atomicAdd(&cnt, z);
        __syncthreads();
        if (threadIdx.x == 0) *flag = (cnt > 1024) ? 1 : 0;
    }
}

__global__ void hist_kernel(const void* __restrict__ ei, const int* __restrict__ flag,
                            int* __restrict__ counts, int E, int N) {
    int e = blockIdx.x * blockDim.x + threadIdx.x;
    if (e >= E) return;
    int f64 = *flag;
    int d = idx_at(ei, (long long)E + e, f64);
    if ((unsigned)d < (unsigned)N) atomicAdd(&counts[d], 1);
}

__device__ __forceinline__ int wave_incl_scan(int v, int lane) {
#pragma unroll
    for (int off = 1; off < 64; off <<= 1) {
        int u = __shfl_up(v, off);
        if (lane >= off) v += u;
    }
    return v;
}

// ---- 3-kernel parallel exclusive scan over PADDED counts (R2/R11) ----
__global__ __launch_bounds__(256) void blocksum_kernel(const int* __restrict__ counts,
                                                       int* __restrict__ bsums, int N) {
    int i = blockIdx.x * 256 + threadIdx.x;
    int v = (i < N) ? ((counts[i] + 7) & ~7) : 0;  // padded to 8
    int lane = threadIdx.x & 63, w = threadIdx.x >> 6;
#pragma unroll
    for (int off = 32; off > 0; off >>= 1) v += __shfl_down(v, off);
    __shared__ int ws[4];
    if (lane == 0) ws[w] = v;
    __syncthreads();
    if (threadIdx.x == 0) bsums[blockIdx.x] = ws[0] + ws[1] + ws[2] + ws[3];
}

__global__ __launch_bounds__(256) void scanb_kernel(int* __restrict__ bsums, int nb) {
    int t = threadIdx.x;
    int lane = t & 63, w = t >> 6;
    int v = (t < nb) ? bsums[t] : 0;
    int iv = wave_incl_scan(v, lane);
    __shared__ int wsum[4];
    if (lane == 63) wsum[w] = iv;
    __syncthreads();
    int add = 0;
    for (int k = 0; k < w; ++k) add += wsum[k];
    if (t < nb) bsums[t] = iv - v + add;  // exclusive
}

// R12: also accumulates gcnt from sorted batch (wave-mostly-uniform atomics).
__global__ __launch_bounds__(256) void fill_kernel(const int* __restrict__ counts,
                                                   const int* __restrict__ bsums,
                                                   int* __restrict__ rowstart,
                                                   int* __restrict__ cursor,
                                                   float* __restrict__ dinv,
                                                   const void* __restrict__ batch,
                                                   const int* __restrict__ flag,
                                                   float* __restrict__ gcnt, int N) {
    int i = blockIdx.x * 256 + threadIdx.x;
    int c = (i < N) ? counts[i] : 0;
    int cp = (c + 7) & ~7;                        // padded
    int lane = threadIdx.x & 63, w = threadIdx.x >> 6;
    int iv = wave_incl_scan(cp, lane);
    __shared__ int wsum[4];
    if (lane == 63) wsum[w] = iv;
    __syncthreads();
    int add = bsums[blockIdx.x];
    for (int k = 0; k < w; ++k) add += wsum[k];
    int excl = iv - cp + add;
    if (i < N) {
        rowstart[i] = excl;
        cursor[i] = excl;
        dinv[i] = rsqrtf((float)(c + 1));
        if (i == N - 1) rowstart[N] = excl + cp;
        int g = idx_at(batch, i, *flag);
        if ((unsigned)g < (unsigned)NGRAPH) atomicAdd(&gcnt[g], 1.0f);
    }
}

// R5: stores ONLY csr_src; R8: uint16 (requires N < 65536; here N=50000)
__global__ void scatter_kernel(const void* __restrict__ ei, const int* __restrict__ flag,
                               int* __restrict__ cursor,
                               unsigned short* __restrict__ csr_src, int E, int N) {
    int e = blockIdx.x * blockDim.x + threadIdx.x;
    if (e >= E) return;
    int f64 = *flag;
    int s = idx_at(ei, e, f64);
    int d = idx_at(ei, (long long)E + e, f64);
    if ((unsigned)s >= (unsigned)N || (unsigned)d >= (unsigned)N) return;
    int pos = atomicAdd(&cursor[d], 1);
    csr_src[pos] = (unsigned short)s;
}

// R10/R11 merged prep: blocks [0,24): pack 3x W into fragment-ordered fp16;
// block 24: zero row N of xs/hsA/hsB (gather target of pad indices);
// blocks [25,..): xs = dinv * x in fp16 (pre-scaled layer-1 gather source).
__global__ __launch_bounds__(256) void prep_kernel(const float* __restrict__ x,
                                                   const float* __restrict__ dinv,
                                                   __half2* __restrict__ xs,
                                                   __half2* __restrict__ hsA,
                                                   __half2* __restrict__ hsB,
                                                   const float* __restrict__ W1,
                                                   const float* __restrict__ W2,
                                                   const float* __restrict__ W3,
                                                   half8v* __restrict__ wf,
                                                   int N, int n2) {
    if (blockIdx.x < 24) {
        int which = blockIdx.x >> 3;
        const float* W = which == 0 ? W1 : (which == 1 ? W2 : W3);
        int t = (blockIdx.x & 7) * 256 + threadIdx.x;  // 0..2047
        int lane = t & 63;
        int nt = (t >> 6) & 7;
        int kblk = t >> 9;
        int n = nt * 16 + (lane & 15);
        int kbase = kblk * 32 + (lane >> 4) * 8;
        half8v v;
#pragma unroll
        for (int j = 0; j < 8; ++j) v[j] = (_Float16)W[(size_t)(kbase + j) * 128 + n];
        wf[which * 2048 + t] = v;
    } else if (blockIdx.x == 24) {
        // zero row N of the three gather sources (64 half2 each)
        int t = threadIdx.x;
        __half2 z = __floats2half2_rn(0.f, 0.f);
        if (t < 64) xs[(size_t)N * 64 + t] = z;
        else if (t < 128) hsA[(size_t)N * 64 + (t - 64)] = z;
        else if (t < 192) hsB[(size_t)N * 64 + (t - 128)] = z;
    } else {
        int i = (blockIdx.x - 25) * 256 + threadIdx.x;
        if (i >= n2) return;
        float dv = dinv[i >> 6];
        float2 v = ((const float2*)x)[i];
        xs[i] = __floats2half2_rn(dv * v.x, dv * v.y);
    }
}

// agg[i] = dinv[i] * ( xs[i] + sum_e xs[src_e] )   (rows pre-scaled, R10)
// ONE WAVE PER NODE. R11: padded CSR -> single uniform 8-batch loop; indices
// loaded 8-at-a-time as one uint4; pad slots hit the zero row (L1-resident).
__global__ __launch_bounds__(256) void agg_kernel(const __half2* __restrict__ xs,
                                                  const int* __restrict__ rowstart,
                                                  const unsigned short* __restrict__ csr_src,
                                                  const float* __restrict__ dinv,
                                                  __half2* __restrict__ out, int N) {
    int wid = (blockIdx.x * blockDim.x + threadIdx.x) >> 6;
    int lane = threadIdx.x & 63;
    if (wid >= N) return;
    float di = dinv[wid];
    float2 s0 = __half22float2(xs[(size_t)wid * 64 + lane]);
    float accx = s0.x, accy = s0.y;
    float bccx = 0.f, bccy = 0.f;
    int e0 = rowstart[wid], e1 = rowstart[wid + 1];
    for (int e = e0; e < e1; e += 8) {
        uint4 q = *(const uint4*)(csr_src + e);   // 8 packed uint16 indices
        int s0i = q.x & 0xffff, s1i = q.x >> 16;
        int s2i = q.y & 0xffff, s3i = q.y >> 16;
        int s4i = q.z & 0xffff, s5i = q.z >> 16;
        int s6i = q.w & 0xffff, s7i = q.w >> 16;
        __half2 v0 = xs[(size_t)s0i * 64 + lane];
        __half2 v1 = xs[(size_t)s1i * 64 + lane];
        __half2 v2 = xs[(size_t)s2i * 64 + lane];
        __half2 v3 = xs[(size_t)s3i * 64 + lane];
        __half2 v4 = xs[(size_t)s4i * 64 + lane];
        __half2 v5 = xs[(size_t)s5i * 64 + lane];
        __half2 v6 = xs[(size_t)s6i * 64 + lane];
        __half2 v7 = xs[(size_t)s7i * 64 + lane];
        float2 f0 = __half22float2(v0), f1 = __half22float2(v1);
        float2 f2 = __half22float2(v2), f3 = __half22float2(v3);
        float2 f4 = __half22float2(v4), f5 = __half22float2(v5);
        float2 f6 = __half22float2(v6), f7 = __half22float2(v7);
        accx += f0.x + f2.x; accy += f0.y + f2.y;
        bccx += f1.x + f3.x; bccy += f1.y + f3.y;
        accx += f4.x + f6.x; accy += f4.y + f6.y;
        bccx += f5.x + f7.x; bccy += f5.y + f7.y;
    }
    out[(size_t)wid * 64 + lane] = __floats2half2_rn(di * (accx + bccx),
                                                     di * (accy + bccy));
}

// h = relu(A @ W + b) via v_mfma_f32_16x16x32_f16. A:[M][128] fp16, W frags
// L2-resident. Wave owns 16 rows x 128 cols (32 MFMAs).
// POOL=false (layers 1,2): write O16 = dinv*relu(...) (pre-scaled next-layer
// gather source, R10). POOL=true (layer 3): NO global h write — accumulate
// relu(...) into pooled[] via LDS[128] + per-graph atomic flush (R12; batch
// sorted -> block spans 1-2 graphs; loop is block-uniform).
template <bool POOL>
__global__ __launch_bounds__(256) void gemm_mfma(const __half2* __restrict__ A16,
                                                 const half8v* __restrict__ wf,
                                                 const float* __restrict__ bias,
                                                 const float* __restrict__ dinv,
                                                 __half2* __restrict__ O16,
                                                 const void* __restrict__ batch,
                                                 const int* __restrict__ flag,
                                                 float* __restrict__ pooled, int M) {
    __shared__ float lds_pool[HID];
    int wid = threadIdx.x >> 6, lane = threadIdx.x & 63;
    int rowTile = blockIdx.x * 64 + wid * 16;
    int hi = lane >> 4;
    int arow = rowTile + (lane & 15);
    if (arow >= M) arow = M - 1;  // clamp; outputs guarded below
    const half8v* Arow = (const half8v*)((const _Float16*)A16 + (size_t)arow * 128);

    floatx4 acc[8];
#pragma unroll
    for (int nt = 0; nt < 8; ++nt) acc[nt] = (floatx4){0.f, 0.f, 0.f, 0.f};

#pragma unroll
    for (int kb = 0; kb < 4; ++kb) {
        half8v a = Arow[kb * 4 + hi];
#pragma unroll
        for (int nt = 0; nt < 8; ++nt) {
            half8v w = wf[(kb * 8 + nt) * 64 + lane];
            acc[nt] = __builtin_amdgcn_mfma_f32_16x16x32_f16(a, w, acc[nt], 0, 0, 0);
        }
    }

    // C/D: col = lane&15, row = (lane>>4)*4 + reg   [HW-verified]
    int ocol_lo = lane & 15;
    int orow0 = rowTile + hi * 4;

    if (!POOL) {
        float dv[4];
#pragma unroll
        for (int r = 0; r < 4; ++r) {
            int orow = orow0 + r;
            dv[r] = (orow < M) ? dinv[orow] : 1.0f;
        }
#pragma unroll
        for (int nt = 0; nt < 8; ++nt) {
            int col = nt * 16 + ocol_lo;
            float b = bias[col];
#pragma unroll
            for (int r = 0; r < 4; ++r) {
                int orow = orow0 + r;
                if (orow < M) {
                    float v = fmaxf(acc[nt][r] + b, 0.f) * dv[r];
                    ((_Float16*)O16)[(size_t)orow * 128 + col] = (_Float16)v;
                }
            }
        }
    } else {
        int f64 = *flag;
        int rlo = blockIdx.x * 64;
        int rhi = rlo + 63; if (rhi >= M) rhi = M - 1;
        int gmin = idx_at(batch, rlo, f64);
        int gmax = idx_at(batch, rhi, f64);
        int gr[4];
#pragma unroll
        for (int r = 0; r < 4; ++r) {
            int orow = orow0 + r;
            gr[r] = (orow < M) ? idx_at(batch, orow, f64) : -1;
        }
        for (int g = gmin; g <= gmax; ++g) {
            for (int c = threadIdx.x; c < HID; c += 256) lds_pool[c] = 0.f;
            __syncthreads();
#pragma unroll
            for (int nt = 0; nt < 8; ++nt) {
                int col = nt * 16 + ocol_lo;
                float b = bias[col];
#pragma unroll
                for (int r = 0; r < 4; ++r) {
                    if (gr[r] == g) {
                        float v = fmaxf(acc[nt][r] + b, 0.f);
                        atomicAdd(&lds_pool[col], v);
                    }
                }
            }
            __syncthreads();
            if (threadIdx.x < HID && (unsigned)g < (unsigned)NGRAPH)
                atomicAdd(&pooled[g * HID + threadIdx.x], lds_pool[threadIdx.x]);
            __syncthreads();
        }
    }
}

__global__ __launch_bounds__(128) void final_kernel(const float* __restrict__ pooled,
                                                    const float* __restrict__ gcnt,
                                                    const float* __restrict__ Wl,
                                                    const float* __restrict__ bl,
                                                    float* __restrict__ out) {
    int o = blockIdx.x * blockDim.x + threadIdx.x;
    if (o >= NGRAPH * 10) return;
    int g = o / 10, c = o % 10;
    float inv = 1.0f / fmaxf(gcnt[g], 1.0f);
    float acc = 0.f;
    for (int k = 0; k < HID; ++k)
        acc = fmaf(pooled[g * HID + k], Wl[k * 10 + c], acc);
    out[o] = acc * inv + bl[c];
}

extern "C" void kernel_launch(void* const* d_in, const int* in_sizes, int n_in,
                              void* d_out, int out_size, void* d_ws, size_t ws_size,
                              hipStream_t stream) {
    const float* x   = (const float*)d_in[0];
    const void* ei   = d_in[1];
    const void* bat  = d_in[2];
    const float* W1  = (const float*)d_in[3];
    const float* b1  = (const float*)d_in[4];
    const float* W2  = (const float*)d_in[5];
    const float* b2  = (const float*)d_in[6];
    const float* W3  = (const float*)d_in[7];
    const float* b3  = (const float*)d_in[8];
    const float* Wl  = (const float*)d_in[9];
    const float* bl  = (const float*)d_in[10];
    float* out = (float*)d_out;

    const int N = in_sizes[0] / HID;   // 50000 (< 65536: csr_src is uint16)
    const int E = in_sizes[1] / 2;     // 600000
    const int EPAD = (E + 7 * N + 7) & ~7;   // padded-CSR capacity

    char* w = (char*)d_ws;
    size_t off = 0;
    auto carve = [&](size_t bytes) -> void* {
        void* p = w + off;
        off = (off + bytes + 255) & ~(size_t)255;
        return p;
    };
    __half2* xs       = (__half2*)carve((size_t)(N + 1) * HID * 2); // dinv*x (+zero row)
    __half2* aggB16   = (__half2*)carve((size_t)N * HID * 2);       // agg out (GEMM A)
    __half2* hsA      = (__half2*)carve((size_t)(N + 1) * HID * 2); // dinv*h1 (+zero)
    __half2* hsB      = (__half2*)carve((size_t)(N + 1) * HID * 2); // dinv*h2 (+zero)
    int*     counts   = (int*)carve((size_t)N * 4);
    int*     rowstart = (int*)carve((size_t)(N + 1) * 4);
    int*     cursor   = (int*)carve((size_t)N * 4);
    float*   dinv     = (float*)carve((size_t)N * 4);
    unsigned short* csr_src = (unsigned short*)carve((size_t)EPAD * 2);
    float*   pooled   = (float*)carve((size_t)NGRAPH * HID * 4);
    float*   gcnt     = (float*)carve((size_t)NGRAPH * 4);
    half8v*  wf       = (half8v*)carve(3 * 2048 * 16);              // 3 packed W
    int*     bsums    = (int*)carve(1024);
    int*     flag     = (int*)carve(256);

    const int nb = (N + 255) / 256;
    const int n2 = N * HID / 2;

    // graph preprocessing (once; shared by all 3 layers)
    init_kernel<<<nb, 256, 0, stream>>>((const int*)ei, flag, counts, pooled, gcnt,
                                        (uint4*)csr_src, N, EPAD / 8);
    hist_kernel<<<(E + 255) / 256, 256, 0, stream>>>(ei, flag, counts, E, N);
    blocksum_kernel<<<nb, 256, 0, stream>>>(counts, bsums, N);
    scanb_kernel<<<1, 256, 0, stream>>>(bsums, nb);
    fill_kernel<<<nb, 256, 0, stream>>>(counts, bsums, rowstart, cursor, dinv,
                                        bat, flag, gcnt, N);
    scatter_kernel<<<(E + 255) / 256, 256, 0, stream>>>(ei, flag, cursor, csr_src, E, N);
    prep_kernel<<<25 + (n2 + 255) / 256, 256, 0, stream>>>(x, dinv, xs, hsA, hsB,
                                                           W1, W2, W3, wf, N, n2);

    int aggBlocks  = (N + 3) / 4;        // one wave per node, 4 waves/block
    int gemmBlocks = (N + 63) / 64;      // 64 rows/block (4 waves x 16 rows)

    // layer 1
    agg_kernel<<<aggBlocks, 256, 0, stream>>>(xs, rowstart, csr_src, dinv, aggB16, N);
    gemm_mfma<false><<<gemmBlocks, 256, 0, stream>>>(aggB16, wf, b1, dinv, hsA,
                                                     bat, flag, pooled, N);
    // layer 2
    agg_kernel<<<aggBlocks, 256, 0, stream>>>(hsA, rowstart, csr_src, dinv, aggB16, N);
    gemm_mfma<false><<<gemmBlocks, 256, 0, stream>>>(aggB16, wf + 2048, b2, dinv, hsB,
                                                     bat, flag, pooled, N);
    // layer 3: GEMM + fused mean-pool accumulation (no h3 write)
    agg_kernel<<<aggBlocks, 256, 0, stream>>>(hsB, rowstart, csr_src, dinv, aggB16, N);
    gemm_mfma<true><<<gemmBlocks, 256, 0, stream>>>(aggB16, wf + 4096, b3, dinv, nullptr,
                                                    bat, flag, pooled, N);

    // final linear (pooled sums / gcnt)
    final_kernel<<<5, 128, 0, stream>>>(pooled, gcnt, Wl, bl, out);
}

// Round 14
// 243.664 us; speedup vs baseline: 2.2047x; 2.2047x over previous
//
#include <hip/hip_runtime.h>
#include <hip/hip_bf16.h>
#include <hip/hip_fp16.h>

// ---------------------------------------------------------------------------
// GCN graph classifier: 3x GCNConv(128->128) + ReLU, mean-pool(64), linear(10)
// Strategy:
//   * R13: gcnt via BINARY SEARCH on sorted batch inside final_kernel
//     (R12's per-node atomicAdd(&gcnt[g]) serialized on 64 hot words ->
//     fill_kernel 3->303us. Zero-atomic replacement.)
//   * R12: mean-pool FUSED into layer-3 GEMM epilogue (LDS[128] accumulate +
//     per-graph flush; batch sorted -> block spans 1-2 graphs). ~neutral vs
//     separate pool; kept for lower kernel count. Falsifier: >236us -> unfuse.
//   * R11: 8-aligned padded CSR; pad slots -> index N (appended zero row);
//     agg inner loop = single uniform 8-batch (uint4 = 8 packed u16 indices).
//   * R10: rows PRE-SCALED by dinv (xs = dinv*x; hs = dinv*relu(...)), agg =
//     pure row sum * dinv[i] (reassociation of D^-1/2 A D^-1/2).
//   * R9: one wave per node (R8 fusion cut gather TLP 16x -> regressed).
//   * R8: csr_src uint16; R7: MFMA GEMM w/ pre-packed W frags
//     (C/D col=lane&15,row=(lane>>4)*4+reg [HW-verified]); R6: fp16 rows;
//     R2: 3-kernel parallel scan.
// ---------------------------------------------------------------------------

#define HID 128
#define NGRAPH 64

typedef _Float16 half8v __attribute__((ext_vector_type(8)));
typedef float floatx4 __attribute__((ext_vector_type(4)));

__device__ __forceinline__ int idx_at(const void* p, long long i, int f64) {
    if (f64) return (int)((const long long*)p)[i];
    return ((const int*)p)[i];
}

// init counts/pooled + fill padded csr_src with N (zero-row index);
// block 0 also detects int64-vs-int32 edge_index (odd 32-bit words all zero).
__global__ void init_kernel(const int* __restrict__ ei, int* __restrict__ flag,
                            int* __restrict__ counts, float* __restrict__ pooled,
                            uint4* __restrict__ csr4, int N, int nCsr4) {
    int i = blockIdx.x * blockDim.x + threadIdx.x;
    int stride = gridDim.x * blockDim.x;
    if (i < N) counts[i] = 0;
    if (i < NGRAPH * HID) pooled[i] = 0.f;
    unsigned fillv = (unsigned)N | ((unsigned)N << 16);
    uint4 fv = make_uint4(fillv, fillv, fillv, fillv);
    for (int j = i; j < nCsr4; j += stride) csr4[j] = fv;
    if (blockIdx.x == 0) {
        __shared__ int cnt;
        if (threadIdx.x == 0) cnt = 0;
        __syncthreads();
        int z = 0;
        for (int k = threadIdx.x; k < 2048; k += 256)
            if (ei[2 * k + 1] == 0) z++;
        atomicAdd(&cnt, z);
        __syncthreads();
        if (threadIdx.x == 0) *flag = (cnt > 1024) ? 1 : 0;
    }
}

__global__ void hist_kernel(const void* __restrict__ ei, const int* __restrict__ flag,
                            int* __restrict__ counts, int E, int N) {
    int e = blockIdx.x * blockDim.x + threadIdx.x;
    if (e >= E) return;
    int f64 = *flag;
    int d = idx_at(ei, (long long)E + e, f64);
    if ((unsigned)d < (unsigned)N) atomicAdd(&counts[d], 1);
}

__device__ __forceinline__ int wave_incl_scan(int v, int lane) {
#pragma unroll
    for (int off = 1; off < 64; off <<= 1) {
        int u = __shfl_up(v, off);
        if (lane >= off) v += u;
    }
    return v;
}

// ---- 3-kernel parallel exclusive scan over PADDED counts (R2/R11) ----
__global__ __launch_bounds__(256) void blocksum_kernel(const int* __restrict__ counts,
                                                       int* __restrict__ bsums, int N) {
    int i = blockIdx.x * 256 + threadIdx.x;
    int v = (i < N) ? ((counts[i] + 7) & ~7) : 0;  // padded to 8
    int lane = threadIdx.x & 63, w = threadIdx.x >> 6;
#pragma unroll
    for (int off = 32; off > 0; off >>= 1) v += __shfl_down(v, off);
    __shared__ int ws[4];
    if (lane == 0) ws[w] = v;
    __syncthreads();
    if (threadIdx.x == 0) bsums[blockIdx.x] = ws[0] + ws[1] + ws[2] + ws[3];
}

__global__ __launch_bounds__(256) void scanb_kernel(int* __restrict__ bsums, int nb) {
    int t = threadIdx.x;
    int lane = t & 63, w = t >> 6;
    int v = (t < nb) ? bsums[t] : 0;
    int iv = wave_incl_scan(v, lane);
    __shared__ int wsum[4];
    if (lane == 63) wsum[w] = iv;
    __syncthreads();
    int add = 0;
    for (int k = 0; k < w; ++k) add += wsum[k];
    if (t < nb) bsums[t] = iv - v + add;  // exclusive
}

// R13: reverted to clean R11 form (no batch/gcnt work here).
__global__ __launch_bounds__(256) void fill_kernel(const int* __restrict__ counts,
                                                   const int* __restrict__ bsums,
                                                   int* __restrict__ rowstart,
                                                   int* __restrict__ cursor,
                                                   float* __restrict__ dinv, int N) {
    int i = blockIdx.x * 256 + threadIdx.x;
    int c = (i < N) ? counts[i] : 0;
    int cp = (c + 7) & ~7;                        // padded
    int lane = threadIdx.x & 63, w = threadIdx.x >> 6;
    int iv = wave_incl_scan(cp, lane);
    __shared__ int wsum[4];
    if (lane == 63) wsum[w] = iv;
    __syncthreads();
    int add = bsums[blockIdx.x];
    for (int k = 0; k < w; ++k) add += wsum[k];
    int excl = iv - cp + add;
    if (i < N) {
        rowstart[i] = excl;
        cursor[i] = excl;
        dinv[i] = rsqrtf((float)(c + 1));
        if (i == N - 1) rowstart[N] = excl + cp;
    }
}

// R5: stores ONLY csr_src; R8: uint16 (requires N < 65536; here N=50000)
__global__ void scatter_kernel(const void* __restrict__ ei, const int* __restrict__ flag,
                               int* __restrict__ cursor,
                               unsigned short* __restrict__ csr_src, int E, int N) {
    int e = blockIdx.x * blockDim.x + threadIdx.x;
    if (e >= E) return;
    int f64 = *flag;
    int s = idx_at(ei, e, f64);
    int d = idx_at(ei, (long long)E + e, f64);
    if ((unsigned)s >= (unsigned)N || (unsigned)d >= (unsigned)N) return;
    int pos = atomicAdd(&cursor[d], 1);
    csr_src[pos] = (unsigned short)s;
}

// R10/R11 merged prep: blocks [0,24): pack 3x W into fragment-ordered fp16;
// block 24: zero row N of xs/hsA/hsB (gather target of pad indices);
// blocks [25,..): xs = dinv * x in fp16 (pre-scaled layer-1 gather source).
__global__ __launch_bounds__(256) void prep_kernel(const float* __restrict__ x,
                                                   const float* __restrict__ dinv,
                                                   __half2* __restrict__ xs,
                                                   __half2* __restrict__ hsA,
                                                   __half2* __restrict__ hsB,
                                                   const float* __restrict__ W1,
                                                   const float* __restrict__ W2,
                                                   const float* __restrict__ W3,
                                                   half8v* __restrict__ wf,
                                                   int N, int n2) {
    if (blockIdx.x < 24) {
        int which = blockIdx.x >> 3;
        const float* W = which == 0 ? W1 : (which == 1 ? W2 : W3);
        int t = (blockIdx.x & 7) * 256 + threadIdx.x;  // 0..2047
        int lane = t & 63;
        int nt = (t >> 6) & 7;
        int kblk = t >> 9;
        int n = nt * 16 + (lane & 15);
        int kbase = kblk * 32 + (lane >> 4) * 8;
        half8v v;
#pragma unroll
        for (int j = 0; j < 8; ++j) v[j] = (_Float16)W[(size_t)(kbase + j) * 128 + n];
        wf[which * 2048 + t] = v;
    } else if (blockIdx.x == 24) {
        // zero row N of the three gather sources (64 half2 each)
        int t = threadIdx.x;
        __half2 z = __floats2half2_rn(0.f, 0.f);
        if (t < 64) xs[(size_t)N * 64 + t] = z;
        else if (t < 128) hsA[(size_t)N * 64 + (t - 64)] = z;
        else if (t < 192) hsB[(size_t)N * 64 + (t - 128)] = z;
    } else {
        int i = (blockIdx.x - 25) * 256 + threadIdx.x;
        if (i >= n2) return;
        float dv = dinv[i >> 6];
        float2 v = ((const float2*)x)[i];
        xs[i] = __floats2half2_rn(dv * v.x, dv * v.y);
    }
}

// agg[i] = dinv[i] * ( xs[i] + sum_e xs[src_e] )   (rows pre-scaled, R10)
// ONE WAVE PER NODE. R11: padded CSR -> single uniform 8-batch loop; indices
// loaded 8-at-a-time as one uint4; pad slots hit the zero row (L1-resident).
__global__ __launch_bounds__(256) void agg_kernel(const __half2* __restrict__ xs,
                                                  const int* __restrict__ rowstart,
                                                  const unsigned short* __restrict__ csr_src,
                                                  const float* __restrict__ dinv,
                                                  __half2* __restrict__ out, int N) {
    int wid = (blockIdx.x * blockDim.x + threadIdx.x) >> 6;
    int lane = threadIdx.x & 63;
    if (wid >= N) return;
    float di = dinv[wid];
    float2 s0 = __half22float2(xs[(size_t)wid * 64 + lane]);
    float accx = s0.x, accy = s0.y;
    float bccx = 0.f, bccy = 0.f;
    int e0 = rowstart[wid], e1 = rowstart[wid + 1];
    for (int e = e0; e < e1; e += 8) {
        uint4 q = *(const uint4*)(csr_src + e);   // 8 packed uint16 indices
        int s0i = q.x & 0xffff, s1i = q.x >> 16;
        int s2i = q.y & 0xffff, s3i = q.y >> 16;
        int s4i = q.z & 0xffff, s5i = q.z >> 16;
        int s6i = q.w & 0xffff, s7i = q.w >> 16;
        __half2 v0 = xs[(size_t)s0i * 64 + lane];
        __half2 v1 = xs[(size_t)s1i * 64 + lane];
        __half2 v2 = xs[(size_t)s2i * 64 + lane];
        __half2 v3 = xs[(size_t)s3i * 64 + lane];
        __half2 v4 = xs[(size_t)s4i * 64 + lane];
        __half2 v5 = xs[(size_t)s5i * 64 + lane];
        __half2 v6 = xs[(size_t)s6i * 64 + lane];
        __half2 v7 = xs[(size_t)s7i * 64 + lane];
        float2 f0 = __half22float2(v0), f1 = __half22float2(v1);
        float2 f2 = __half22float2(v2), f3 = __half22float2(v3);
        float2 f4 = __half22float2(v4), f5 = __half22float2(v5);
        float2 f6 = __half22float2(v6), f7 = __half22float2(v7);
        accx += f0.x + f2.x; accy += f0.y + f2.y;
        bccx += f1.x + f3.x; bccy += f1.y + f3.y;
        accx += f4.x + f6.x; accy += f4.y + f6.y;
        bccx += f5.x + f7.x; bccy += f5.y + f7.y;
    }
    out[(size_t)wid * 64 + lane] = __floats2half2_rn(di * (accx + bccx),
                                                     di * (accy + bccy));
}

// h = relu(A @ W + b) via v_mfma_f32_16x16x32_f16. A:[M][128] fp16, W frags
// L2-resident. Wave owns 16 rows x 128 cols (32 MFMAs).
// POOL=false (layers 1,2): write O16 = dinv*relu(...) (pre-scaled next-layer
// gather source, R10). POOL=true (layer 3): NO global h write — accumulate
// relu(...) into pooled[] via LDS[128] + per-graph atomic flush (R12; batch
// sorted -> block spans 1-2 graphs; loop is block-uniform).
template <bool POOL>
__global__ __launch_bounds__(256) void gemm_mfma(const __half2* __restrict__ A16,
                                                 const half8v* __restrict__ wf,
                                                 const float* __restrict__ bias,
                                                 const float* __restrict__ dinv,
                                                 __half2* __restrict__ O16,
                                                 const void* __restrict__ batch,
                                                 const int* __restrict__ flag,
                                                 float* __restrict__ pooled, int M) {
    __shared__ float lds_pool[HID];
    int wid = threadIdx.x >> 6, lane = threadIdx.x & 63;
    int rowTile = blockIdx.x * 64 + wid * 16;
    int hi = lane >> 4;
    int arow = rowTile + (lane & 15);
    if (arow >= M) arow = M - 1;  // clamp; outputs guarded below
    const half8v* Arow = (const half8v*)((const _Float16*)A16 + (size_t)arow * 128);

    floatx4 acc[8];
#pragma unroll
    for (int nt = 0; nt < 8; ++nt) acc[nt] = (floatx4){0.f, 0.f, 0.f, 0.f};

#pragma unroll
    for (int kb = 0; kb < 4; ++kb) {
        half8v a = Arow[kb * 4 + hi];
#pragma unroll
        for (int nt = 0; nt < 8; ++nt) {
            half8v w = wf[(kb * 8 + nt) * 64 + lane];
            acc[nt] = __builtin_amdgcn_mfma_f32_16x16x32_f16(a, w, acc[nt], 0, 0, 0);
        }
    }

    // C/D: col = lane&15, row = (lane>>4)*4 + reg   [HW-verified]
    int ocol_lo = lane & 15;
    int orow0 = rowTile + hi * 4;

    if (!POOL) {
        float dv[4];
#pragma unroll
        for (int r = 0; r < 4; ++r) {
            int orow = orow0 + r;
            dv[r] = (orow < M) ? dinv[orow] : 1.0f;
        }
#pragma unroll
        for (int nt = 0; nt < 8; ++nt) {
            int col = nt * 16 + ocol_lo;
            float b = bias[col];
#pragma unroll
            for (int r = 0; r < 4; ++r) {
                int orow = orow0 + r;
                if (orow < M) {
                    float v = fmaxf(acc[nt][r] + b, 0.f) * dv[r];
                    ((_Float16*)O16)[(size_t)orow * 128 + col] = (_Float16)v;
                }
            }
        }
    } else {
        int f64 = *flag;
        int rlo = blockIdx.x * 64;
        int rhi = rlo + 63; if (rhi >= M) rhi = M - 1;
        int gmin = idx_at(batch, rlo, f64);
        int gmax = idx_at(batch, rhi, f64);
        int gr[4];
#pragma unroll
        for (int r = 0; r < 4; ++r) {
            int orow = orow0 + r;
            gr[r] = (orow < M) ? idx_at(batch, orow, f64) : -1;
        }
        for (int g = gmin; g <= gmax; ++g) {
            for (int c = threadIdx.x; c < HID; c += 256) lds_pool[c] = 0.f;
            __syncthreads();
#pragma unroll
            for (int nt = 0; nt < 8; ++nt) {
                int col = nt * 16 + ocol_lo;
                float b = bias[col];
#pragma unroll
                for (int r = 0; r < 4; ++r) {
                    if (gr[r] == g) {
                        float v = fmaxf(acc[nt][r] + b, 0.f);
                        atomicAdd(&lds_pool[col], v);
                    }
                }
            }
            __syncthreads();
            if (threadIdx.x < HID && (unsigned)g < (unsigned)NGRAPH)
                atomicAdd(&pooled[g * HID + threadIdx.x], lds_pool[threadIdx.x]);
            __syncthreads();
        }
    }
}

// R13: per-graph node count via binary search on sorted batch (no atomics).
__global__ __launch_bounds__(128) void final_kernel(const float* __restrict__ pooled,
                                                    const void* __restrict__ batch,
                                                    const int* __restrict__ flag,
                                                    const float* __restrict__ Wl,
                                                    const float* __restrict__ bl,
                                                    float* __restrict__ out, int N) {
    int o = blockIdx.x * blockDim.x + threadIdx.x;
    if (o >= NGRAPH * 10) return;
    int g = o / 10, c = o % 10;
    int f64 = *flag;
    auto lb = [&](int val) {
        int lo = 0, hi = N;
        while (lo < hi) {
            int mid = (lo + hi) >> 1;
            if (idx_at(batch, mid, f64) < val) lo = mid + 1; else hi = mid;
        }
        return lo;
    };
    int cnt = lb(g + 1) - lb(g);
    float inv = 1.0f / fmaxf((float)cnt, 1.0f);
    float acc = 0.f;
    for (int k = 0; k < HID; ++k)
        acc = fmaf(pooled[g * HID + k], Wl[k * 10 + c], acc);
    out[o] = acc * inv + bl[c];
}

extern "C" void kernel_launch(void* const* d_in, const int* in_sizes, int n_in,
                              void* d_out, int out_size, void* d_ws, size_t ws_size,
                              hipStream_t stream) {
    const float* x   = (const float*)d_in[0];
    const void* ei   = d_in[1];
    const void* bat  = d_in[2];
    const float* W1  = (const float*)d_in[3];
    const float* b1  = (const float*)d_in[4];
    const float* W2  = (const float*)d_in[5];
    const float* b2  = (const float*)d_in[6];
    const float* W3  = (const float*)d_in[7];
    const float* b3  = (const float*)d_in[8];
    const float* Wl  = (const float*)d_in[9];
    const float* bl  = (const float*)d_in[10];
    float* out = (float*)d_out;

    const int N = in_sizes[0] / HID;   // 50000 (< 65536: csr_src is uint16)
    const int E = in_sizes[1] / 2;     // 600000
    const int EPAD = (E + 7 * N + 7) & ~7;   // padded-CSR capacity

    char* w = (char*)d_ws;
    size_t off = 0;
    auto carve = [&](size_t bytes) -> void* {
        void* p = w + off;
        off = (off + bytes + 255) & ~(size_t)255;
        return p;
    };
    __half2* xs       = (__half2*)carve((size_t)(N + 1) * HID * 2); // dinv*x (+zero row)
    __half2* aggB16   = (__half2*)carve((size_t)N * HID * 2);       // agg out (GEMM A)
    __half2* hsA      = (__half2*)carve((size_t)(N + 1) * HID * 2); // dinv*h1 (+zero)
    __half2* hsB      = (__half2*)carve((size_t)(N + 1) * HID * 2); // dinv*h2 (+zero)
    int*     counts   = (int*)carve((size_t)N * 4);
    int*     rowstart = (int*)carve((size_t)(N + 1) * 4);
    int*     cursor   = (int*)carve((size_t)N * 4);
    float*   dinv     = (float*)carve((size_t)N * 4);
    unsigned short* csr_src = (unsigned short*)carve((size_t)EPAD * 2);
    float*   pooled   = (float*)carve((size_t)NGRAPH * HID * 4);
    half8v*  wf       = (half8v*)carve(3 * 2048 * 16);              // 3 packed W
    int*     bsums    = (int*)carve(1024);
    int*     flag     = (int*)carve(256);

    const int nb = (N + 255) / 256;
    const int n2 = N * HID / 2;

    // graph preprocessing (once; shared by all 3 layers)
    init_kernel<<<nb, 256, 0, stream>>>((const int*)ei, flag, counts, pooled,
                                        (uint4*)csr_src, N, EPAD / 8);
    hist_kernel<<<(E + 255) / 256, 256, 0, stream>>>(ei, flag, counts, E, N);
    blocksum_kernel<<<nb, 256, 0, stream>>>(counts, bsums, N);
    scanb_kernel<<<1, 256, 0, stream>>>(bsums, nb);
    fill_kernel<<<nb, 256, 0, stream>>>(counts, bsums, rowstart, cursor, dinv, N);
    scatter_kernel<<<(E + 255) / 256, 256, 0, stream>>>(ei, flag, cursor, csr_src, E, N);
    prep_kernel<<<25 + (n2 + 255) / 256, 256, 0, stream>>>(x, dinv, xs, hsA, hsB,
                                                           W1, W2, W3, wf, N, n2);

    int aggBlocks  = (N + 3) / 4;        // one wave per node, 4 waves/block
    int gemmBlocks = (N + 63) / 64;      // 64 rows/block (4 waves x 16 rows)

    // layer 1
    agg_kernel<<<aggBlocks, 256, 0, stream>>>(xs, rowstart, csr_src, dinv, aggB16, N);
    gemm_mfma<false><<<gemmBlocks, 256, 0, stream>>>(aggB16, wf, b1, dinv, hsA,
                                                     bat, flag, pooled, N);
    // layer 2
    agg_kernel<<<aggBlocks, 256, 0, stream>>>(hsA, rowstart, csr_src, dinv, aggB16, N);
    gemm_mfma<false><<<gemmBlocks, 256, 0, stream>>>(aggB16, wf + 2048, b2, dinv, hsB,
                                                     bat, flag, pooled, N);
    // layer 3: GEMM + fused mean-pool accumulation (no h3 write)
    agg_kernel<<<aggBlocks, 256, 0, stream>>>(hsB, rowstart, csr_src, dinv, aggB16, N);
    gemm_mfma<true><<<gemmBlocks, 256, 0, stream>>>(aggB16, wf + 4096, b3, dinv, nullptr,
                                                    bat, flag, pooled, N);

    // final linear (pooled sums / binary-searched counts)
    final_kernel<<<5, 128, 0, stream>>>(pooled, bat, flag, Wl, bl, out, N);
}

// Round 15
// 221.397 us; speedup vs baseline: 2.4264x; 1.1006x over previous
//
#include <hip/hip_runtime.h>
#include <hip/hip_bf16.h>
#include <hip/hip_fp16.h>

// ---------------------------------------------------------------------------
// GCN graph classifier: 3x GCNConv(128->128) + ReLU, mean-pool(64), linear(10)
// Strategy:
//   * R14: UNFUSED pool (R12 fusion's per-graph 128-atomic flush serialized on
//     ~4 hot cache lines cross-XCD -> 51us epilogue; separate pool ~8us).
//     Third instance of the hot-line lesson (R12 gcnt, R13 fix, R14 unfuse).
//   * R13 (kept): graph counts via binary search on sorted batch in final
//     (zero atomics).
//   * R11: 8-aligned padded CSR; pad slots -> index N (appended zero row);
//     agg inner loop = single uniform 8-batch (uint4 = 8 packed u16 indices).
//   * R10: rows PRE-SCALED by dinv (xs = dinv*x; hs = dinv*relu(...)), agg =
//     pure row sum * dinv[i] (reassociation of D^-1/2 A D^-1/2).
//   * R9: one wave per node (R8 fusion cut gather TLP 16x -> regressed);
//     h3 + pooling fp16.
//   * R8: csr_src uint16; R7: MFMA GEMM w/ pre-packed W frags
//     (C/D col=lane&15,row=(lane>>4)*4+reg [HW-verified]); R6: fp16 rows;
//     R2: 3-kernel parallel scan.
// ---------------------------------------------------------------------------

#define HID 128
#define NGRAPH 64

typedef _Float16 half8v __attribute__((ext_vector_type(8)));
typedef float floatx4 __attribute__((ext_vector_type(4)));

__device__ __forceinline__ int idx_at(const void* p, long long i, int f64) {
    if (f64) return (int)((const long long*)p)[i];
    return ((const int*)p)[i];
}

// init counts/pooled + fill padded csr_src with N (zero-row index);
// block 0 also detects int64-vs-int32 edge_index (odd 32-bit words all zero).
__global__ void init_kernel(const int* __restrict__ ei, int* __restrict__ flag,
                            int* __restrict__ counts, float* __restrict__ pooled,
                            uint4* __restrict__ csr4, int N, int nCsr4) {
    int i = blockIdx.x * blockDim.x + threadIdx.x;
    int stride = gridDim.x * blockDim.x;
    if (i < N) counts[i] = 0;
    if (i < NGRAPH * HID) pooled[i] = 0.f;
    unsigned fillv = (unsigned)N | ((unsigned)N << 16);
    uint4 fv = make_uint4(fillv, fillv, fillv, fillv);
    for (int j = i; j < nCsr4; j += stride) csr4[j] = fv;
    if (blockIdx.x == 0) {
        __shared__ int cnt;
        if (threadIdx.x == 0) cnt = 0;
        __syncthreads();
        int z = 0;
        for (int k = threadIdx.x; k < 2048; k += 256)
            if (ei[2 * k + 1] == 0) z++;
        atomicAdd(&cnt, z);
        __syncthreads();
        if (threadIdx.x == 0) *flag = (cnt > 1024) ? 1 : 0;
    }
}

__global__ void hist_kernel(const void* __restrict__ ei, const int* __restrict__ flag,
                            int* __restrict__ counts, int E, int N) {
    int e = blockIdx.x * blockDim.x + threadIdx.x;
    if (e >= E) return;
    int f64 = *flag;
    int d = idx_at(ei, (long long)E + e, f64);
    if ((unsigned)d < (unsigned)N) atomicAdd(&counts[d], 1);
}

__device__ __forceinline__ int wave_incl_scan(int v, int lane) {
#pragma unroll
    for (int off = 1; off < 64; off <<= 1) {
        int u = __shfl_up(v, off);
        if (lane >= off) v += u;
    }
    return v;
}

// ---- 3-kernel parallel exclusive scan over PADDED counts (R2/R11) ----
__global__ __launch_bounds__(256) void blocksum_kernel(const int* __restrict__ counts,
                                                       int* __restrict__ bsums, int N) {
    int i = blockIdx.x * 256 + threadIdx.x;
    int v = (i < N) ? ((counts[i] + 7) & ~7) : 0;  // padded to 8
    int lane = threadIdx.x & 63, w = threadIdx.x >> 6;
#pragma unroll
    for (int off = 32; off > 0; off >>= 1) v += __shfl_down(v, off);
    __shared__ int ws[4];
    if (lane == 0) ws[w] = v;
    __syncthreads();
    if (threadIdx.x == 0) bsums[blockIdx.x] = ws[0] + ws[1] + ws[2] + ws[3];
}

__global__ __launch_bounds__(256) void scanb_kernel(int* __restrict__ bsums, int nb) {
    int t = threadIdx.x;
    int lane = t & 63, w = t >> 6;
    int v = (t < nb) ? bsums[t] : 0;
    int iv = wave_incl_scan(v, lane);
    __shared__ int wsum[4];
    if (lane == 63) wsum[w] = iv;
    __syncthreads();
    int add = 0;
    for (int k = 0; k < w; ++k) add += wsum[k];
    if (t < nb) bsums[t] = iv - v + add;  // exclusive
}

__global__ __launch_bounds__(256) void fill_kernel(const int* __restrict__ counts,
                                                   const int* __restrict__ bsums,
                                                   int* __restrict__ rowstart,
                                                   int* __restrict__ cursor,
                                                   float* __restrict__ dinv, int N) {
    int i = blockIdx.x * 256 + threadIdx.x;
    int c = (i < N) ? counts[i] : 0;
    int cp = (c + 7) & ~7;                        // padded
    int lane = threadIdx.x & 63, w = threadIdx.x >> 6;
    int iv = wave_incl_scan(cp, lane);
    __shared__ int wsum[4];
    if (lane == 63) wsum[w] = iv;
    __syncthreads();
    int add = bsums[blockIdx.x];
    for (int k = 0; k < w; ++k) add += wsum[k];
    int excl = iv - cp + add;
    if (i < N) {
        rowstart[i] = excl;
        cursor[i] = excl;
        dinv[i] = rsqrtf((float)(c + 1));
        if (i == N - 1) rowstart[N] = excl + cp;
    }
}

// R5: stores ONLY csr_src; R8: uint16 (requires N < 65536; here N=50000)
__global__ void scatter_kernel(const void* __restrict__ ei, const int* __restrict__ flag,
                               int* __restrict__ cursor,
                               unsigned short* __restrict__ csr_src, int E, int N) {
    int e = blockIdx.x * blockDim.x + threadIdx.x;
    if (e >= E) return;
    int f64 = *flag;
    int s = idx_at(ei, e, f64);
    int d = idx_at(ei, (long long)E + e, f64);
    if ((unsigned)s >= (unsigned)N || (unsigned)d >= (unsigned)N) return;
    int pos = atomicAdd(&cursor[d], 1);
    csr_src[pos] = (unsigned short)s;
}

// R10/R11 merged prep: blocks [0,24): pack 3x W into fragment-ordered fp16;
// block 24: zero row N of xs/hsA/hsB (gather target of pad indices);
// blocks [25,..): xs = dinv * x in fp16 (pre-scaled layer-1 gather source).
__global__ __launch_bounds__(256) void prep_kernel(const float* __restrict__ x,
                                                   const float* __restrict__ dinv,
                                                   __half2* __restrict__ xs,
                                                   __half2* __restrict__ hsA,
                                                   __half2* __restrict__ hsB,
                                                   const float* __restrict__ W1,
                                                   const float* __restrict__ W2,
                                                   const float* __restrict__ W3,
                                                   half8v* __restrict__ wf,
                                                   int N, int n2) {
    if (blockIdx.x < 24) {
        int which = blockIdx.x >> 3;
        const float* W = which == 0 ? W1 : (which == 1 ? W2 : W3);
        int t = (blockIdx.x & 7) * 256 + threadIdx.x;  // 0..2047
        int lane = t & 63;
        int nt = (t >> 6) & 7;
        int kblk = t >> 9;
        int n = nt * 16 + (lane & 15);
        int kbase = kblk * 32 + (lane >> 4) * 8;
        half8v v;
#pragma unroll
        for (int j = 0; j < 8; ++j) v[j] = (_Float16)W[(size_t)(kbase + j) * 128 + n];
        wf[which * 2048 + t] = v;
    } else if (blockIdx.x == 24) {
        // zero row N of the three gather sources (64 half2 each)
        int t = threadIdx.x;
        __half2 z = __floats2half2_rn(0.f, 0.f);
        if (t < 64) xs[(size_t)N * 64 + t] = z;
        else if (t < 128) hsA[(size_t)N * 64 + (t - 64)] = z;
        else if (t < 192) hsB[(size_t)N * 64 + (t - 128)] = z;
    } else {
        int i = (blockIdx.x - 25) * 256 + threadIdx.x;
        if (i >= n2) return;
        float dv = dinv[i >> 6];
        float2 v = ((const float2*)x)[i];
        xs[i] = __floats2half2_rn(dv * v.x, dv * v.y);
    }
}

// agg[i] = dinv[i] * ( xs[i] + sum_e xs[src_e] )   (rows pre-scaled, R10)
// ONE WAVE PER NODE. R11: padded CSR -> single uniform 8-batch loop; indices
// loaded 8-at-a-time as one uint4; pad slots hit the zero row (L1-resident).
__global__ __launch_bounds__(256) void agg_kernel(const __half2* __restrict__ xs,
                                                  const int* __restrict__ rowstart,
                                                  const unsigned short* __restrict__ csr_src,
                                                  const float* __restrict__ dinv,
                                                  __half2* __restrict__ out, int N) {
    int wid = (blockIdx.x * blockDim.x + threadIdx.x) >> 6;
    int lane = threadIdx.x & 63;
    if (wid >= N) return;
    float di = dinv[wid];
    float2 s0 = __half22float2(xs[(size_t)wid * 64 + lane]);
    float accx = s0.x, accy = s0.y;
    float bccx = 0.f, bccy = 0.f;
    int e0 = rowstart[wid], e1 = rowstart[wid + 1];
    for (int e = e0; e < e1; e += 8) {
        uint4 q = *(const uint4*)(csr_src + e);   // 8 packed uint16 indices
        int s0i = q.x & 0xffff, s1i = q.x >> 16;
        int s2i = q.y & 0xffff, s3i = q.y >> 16;
        int s4i = q.z & 0xffff, s5i = q.z >> 16;
        int s6i = q.w & 0xffff, s7i = q.w >> 16;
        __half2 v0 = xs[(size_t)s0i * 64 + lane];
        __half2 v1 = xs[(size_t)s1i * 64 + lane];
        __half2 v2 = xs[(size_t)s2i * 64 + lane];
        __half2 v3 = xs[(size_t)s3i * 64 + lane];
        __half2 v4 = xs[(size_t)s4i * 64 + lane];
        __half2 v5 = xs[(size_t)s5i * 64 + lane];
        __half2 v6 = xs[(size_t)s6i * 64 + lane];
        __half2 v7 = xs[(size_t)s7i * 64 + lane];
        float2 f0 = __half22float2(v0), f1 = __half22float2(v1);
        float2 f2 = __half22float2(v2), f3 = __half22float2(v3);
        float2 f4 = __half22float2(v4), f5 = __half22float2(v5);
        float2 f6 = __half22float2(v6), f7 = __half22float2(v7);
        accx += f0.x + f2.x; accy += f0.y + f2.y;
        bccx += f1.x + f3.x; bccy += f1.y + f3.y;
        accx += f4.x + f6.x; accy += f4.y + f6.y;
        bccx += f5.x + f7.x; bccy += f5.y + f7.y;
    }
    out[(size_t)wid * 64 + lane] = __floats2half2_rn(di * (accx + bccx),
                                                     di * (accy + bccy));
}

// h = relu(A @ W + b) via v_mfma_f32_16x16x32_f16. A:[M][128] fp16, W frags
// L2-resident. No LDS, no barriers. Wave owns 16 rows x 128 cols (32 MFMAs).
// SCALED (layers 1,2): O16 = dinv*relu(...) (pre-scaled next-layer gather
// source, R10). !SCALED (layer 3): plain relu for pooling. (R14: pool-in-
// epilogue fusion reverted — hot-line atomic serialization, 51us.)
template <bool SCALED>
__global__ __launch_bounds__(256) void gemm_mfma(const __half2* __restrict__ A16,
                                                 const half8v* __restrict__ wf,
                                                 const float* __restrict__ bias,
                                                 const float* __restrict__ dinv,
                                                 __half2* __restrict__ O16, int M) {
    int wid = threadIdx.x >> 6, lane = threadIdx.x & 63;
    int rowTile = blockIdx.x * 64 + wid * 16;
    int hi = lane >> 4;
    int arow = rowTile + (lane & 15);
    if (arow >= M) arow = M - 1;  // clamp; outputs guarded below
    const half8v* Arow = (const half8v*)((const _Float16*)A16 + (size_t)arow * 128);

    floatx4 acc[8];
#pragma unroll
    for (int nt = 0; nt < 8; ++nt) acc[nt] = (floatx4){0.f, 0.f, 0.f, 0.f};

#pragma unroll
    for (int kb = 0; kb < 4; ++kb) {
        half8v a = Arow[kb * 4 + hi];
#pragma unroll
        for (int nt = 0; nt < 8; ++nt) {
            half8v w = wf[(kb * 8 + nt) * 64 + lane];
            acc[nt] = __builtin_amdgcn_mfma_f32_16x16x32_f16(a, w, acc[nt], 0, 0, 0);
        }
    }

    // C/D: col = lane&15, row = (lane>>4)*4 + reg   [HW-verified]
    int ocol_lo = lane & 15;
    int orow0 = rowTile + hi * 4;
    float dv[4];
#pragma unroll
    for (int r = 0; r < 4; ++r) {
        int orow = orow0 + r;
        dv[r] = (SCALED && orow < M) ? dinv[orow] : 1.0f;
    }
#pragma unroll
    for (int nt = 0; nt < 8; ++nt) {
        int col = nt * 16 + ocol_lo;
        float b = bias[col];
#pragma unroll
        for (int r = 0; r < 4; ++r) {
            int orow = orow0 + r;
            if (orow < M) {
                float v = fmaxf(acc[nt][r] + b, 0.f);
                if (SCALED) v *= dv[r];
                ((_Float16*)O16)[(size_t)orow * 128 + col] = (_Float16)v;
            }
        }
    }
}

// batch is sorted: one WAVE per 16-node chunk, half2/lane (128 features),
// fp32 accumulate, atomic flush at graph boundaries (R1/R9). Sums only —
// counts come from binary search in final (R13).
#define POOL_CHUNK 16
__global__ __launch_bounds__(256) void pool_kernel(const __half2* __restrict__ h,
                                                   const void* __restrict__ batch,
                                                   const int* __restrict__ flag,
                                                   float* __restrict__ pooled, int N) {
    int wid = (blockIdx.x * blockDim.x + threadIdx.x) >> 6;
    int lane = threadIdx.x & 63;
    int n0 = wid * POOL_CHUNK;
    if (n0 >= N) return;
    int n1 = n0 + POOL_CHUNK; if (n1 > N) n1 = N;
    int f64 = *flag;
    int g = idx_at(batch, n0, f64);
    float ax = 0.f, ay = 0.f;
    for (int n = n0; n < n1; ++n) {
        int gn = idx_at(batch, n, f64);
        if (gn != g) {
            if ((unsigned)g < (unsigned)NGRAPH) {
                atomicAdd(&pooled[g * HID + 2 * lane], ax);
                atomicAdd(&pooled[g * HID + 2 * lane + 1], ay);
            }
            ax = ay = 0.f; g = gn;
        }
        float2 v = __half22float2(h[(size_t)n * 64 + lane]);
        ax += v.x; ay += v.y;
    }
    if ((unsigned)g < (unsigned)NGRAPH) {
        atomicAdd(&pooled[g * HID + 2 * lane], ax);
        atomicAdd(&pooled[g * HID + 2 * lane + 1], ay);
    }
}

// R13: per-graph node count via binary search on sorted batch (no atomics).
__global__ __launch_bounds__(128) void final_kernel(const float* __restrict__ pooled,
                                                    const void* __restrict__ batch,
                                                    const int* __restrict__ flag,
                                                    const float* __restrict__ Wl,
                                                    const float* __restrict__ bl,
                                                    float* __restrict__ out, int N) {
    int o = blockIdx.x * blockDim.x + threadIdx.x;
    if (o >= NGRAPH * 10) return;
    int g = o / 10, c = o % 10;
    int f64 = *flag;
    auto lb = [&](int val) {
        int lo = 0, hi = N;
        while (lo < hi) {
            int mid = (lo + hi) >> 1;
            if (idx_at(batch, mid, f64) < val) lo = mid + 1; else hi = mid;
        }
        return lo;
    };
    int cnt = lb(g + 1) - lb(g);
    float inv = 1.0f / fmaxf((float)cnt, 1.0f);
    float acc = 0.f;
    for (int k = 0; k < HID; ++k)
        acc = fmaf(pooled[g * HID + k], Wl[k * 10 + c], acc);
    out[o] = acc * inv + bl[c];
}

extern "C" void kernel_launch(void* const* d_in, const int* in_sizes, int n_in,
                              void* d_out, int out_size, void* d_ws, size_t ws_size,
                              hipStream_t stream) {
    const float* x   = (const float*)d_in[0];
    const void* ei   = d_in[1];
    const void* bat  = d_in[2];
    const float* W1  = (const float*)d_in[3];
    const float* b1  = (const float*)d_in[4];
    const float* W2  = (const float*)d_in[5];
    const float* b2  = (const float*)d_in[6];
    const float* W3  = (const float*)d_in[7];
    const float* b3  = (const float*)d_in[8];
    const float* Wl  = (const float*)d_in[9];
    const float* bl  = (const float*)d_in[10];
    float* out = (float*)d_out;

    const int N = in_sizes[0] / HID;   // 50000 (< 65536: csr_src is uint16)
    const int E = in_sizes[1] / 2;     // 600000
    const int EPAD = (E + 7 * N + 7) & ~7;   // padded-CSR capacity

    char* w = (char*)d_ws;
    size_t off = 0;
    auto carve = [&](size_t bytes) -> void* {
        void* p = w + off;
        off = (off + bytes + 255) & ~(size_t)255;
        return p;
    };
    __half2* xs       = (__half2*)carve((size_t)(N + 1) * HID * 2); // dinv*x (+zero row)
    __half2* aggB16   = (__half2*)carve((size_t)N * HID * 2);       // agg out (GEMM A)
    __half2* hsA      = (__half2*)carve((size_t)(N + 1) * HID * 2); // dinv*h1 (+zero) / h3
    __half2* hsB      = (__half2*)carve((size_t)(N + 1) * HID * 2); // dinv*h2 (+zero)
    int*     counts   = (int*)carve((size_t)N * 4);
    int*     rowstart = (int*)carve((size_t)(N + 1) * 4);
    int*     cursor   = (int*)carve((size_t)N * 4);
    float*   dinv     = (float*)carve((size_t)N * 4);
    unsigned short* csr_src = (unsigned short*)carve((size_t)EPAD * 2);
    float*   pooled   = (float*)carve((size_t)NGRAPH * HID * 4);
    half8v*  wf       = (half8v*)carve(3 * 2048 * 16);              // 3 packed W
    int*     bsums    = (int*)carve(1024);
    int*     flag     = (int*)carve(256);

    const int nb = (N + 255) / 256;
    const int n2 = N * HID / 2;

    // graph preprocessing (once; shared by all 3 layers)
    init_kernel<<<nb, 256, 0, stream>>>((const int*)ei, flag, counts, pooled,
                                        (uint4*)csr_src, N, EPAD / 8);
    hist_kernel<<<(E + 255) / 256, 256, 0, stream>>>(ei, flag, counts, E, N);
    blocksum_kernel<<<nb, 256, 0, stream>>>(counts, bsums, N);
    scanb_kernel<<<1, 256, 0, stream>>>(bsums, nb);
    fill_kernel<<<nb, 256, 0, stream>>>(counts, bsums, rowstart, cursor, dinv, N);
    scatter_kernel<<<(E + 255) / 256, 256, 0, stream>>>(ei, flag, cursor, csr_src, E, N);
    prep_kernel<<<25 + (n2 + 255) / 256, 256, 0, stream>>>(x, dinv, xs, hsA, hsB,
                                                           W1, W2, W3, wf, N, n2);

    int aggBlocks  = (N + 3) / 4;        // one wave per node, 4 waves/block
    int gemmBlocks = (N + 63) / 64;      // 64 rows/block (4 waves x 16 rows)

    // layer 1
    agg_kernel<<<aggBlocks, 256, 0, stream>>>(xs, rowstart, csr_src, dinv, aggB16, N);
    gemm_mfma<true><<<gemmBlocks, 256, 0, stream>>>(aggB16, wf, b1, dinv, hsA, N);
    // layer 2
    agg_kernel<<<aggBlocks, 256, 0, stream>>>(hsA, rowstart, csr_src, dinv, aggB16, N);
    gemm_mfma<true><<<gemmBlocks, 256, 0, stream>>>(aggB16, wf + 2048, b2, dinv, hsB, N);
    // layer 3 (plain relu h3 into hsA rows < N; zero row untouched)
    agg_kernel<<<aggBlocks, 256, 0, stream>>>(hsB, rowstart, csr_src, dinv, aggB16, N);
    gemm_mfma<false><<<gemmBlocks, 256, 0, stream>>>(aggB16, wf + 4096, b3, dinv, hsA, N);

    // mean pool (fp16 h3) + final linear (binary-searched counts)
    int poolWaves = (N + POOL_CHUNK - 1) / POOL_CHUNK;
    int poolBlocks = (poolWaves + 3) / 4;
    pool_kernel<<<poolBlocks, 256, 0, stream>>>(hsA, bat, flag, pooled, N);
    final_kernel<<<5, 128, 0, stream>>>(pooled, bat, flag, Wl, bl, out, N);
}